// Round 4
// baseline (487.207 us; speedup 1.0000x reference)
//
#include <hip/hip_runtime.h>
#include <hip/hip_fp16.h>

// out[b,o] = sum_{i,n} x[b,i]*noise[b,n]*hW[i*512+o,n]   (branch 0, z=0..31)
//          + sum_{i,n} px[b,i]*noise[b,n]*pW[i*512+o,n]  (branch 1, z=32..63)
//          + sum_i x[b,i]*hb[i*512+o] (+prior)           (E1: K=16 MFMA step)
//          + sum_n noise[b,n]*(hW[MAIN_D+o,n]+pW[..,n])  (E2: macro 17 on ichunk==0)
//          + hb[MAIN_D+o] + pb[MAIN_D+o]                 (init kernel)
// R4: 512 blocks (2/CU) x 512 threads, M=256/N=128 tile, 16 macros/block,
// LDS 77.8KB (W dbuf + 8KB x tile) so two blocks co-reside per CU.

#define MAIN_D (512*512)

typedef _Float16 half8 __attribute__((ext_vector_type(8)));
typedef float floatx4 __attribute__((ext_vector_type(4)));

static __device__ __forceinline__ unsigned pk2(float a, float b) {
    union { __half2 h; unsigned u; } c;
    c.h = __float22half2_rn(make_float2(a, b));
    return c.u;
}

// ---- init: out[b,o] = hb[MAIN_D+o] + pb[MAIN_D+o] ----
__global__ __launch_bounds__(256) void init_kernel(
    const float* __restrict__ hb, const float* __restrict__ pb,
    float* __restrict__ out)
{
    const int idx = blockIdx.x * 256 + threadIdx.x;   // 65536 threads x float4
    const int o4 = (idx * 4) & 511;
    float4 v;
    v.x = hb[MAIN_D + o4 + 0] + pb[MAIN_D + o4 + 0];
    v.y = hb[MAIN_D + o4 + 1] + pb[MAIN_D + o4 + 1];
    v.z = hb[MAIN_D + o4 + 2] + pb[MAIN_D + o4 + 2];
    v.w = hb[MAIN_D + o4 + 3] + pb[MAIN_D + o4 + 3];
    *(float4*)(out + idx * 4) = v;
}

// ---- main: 512 blocks x 512 threads (8 waves, 4m x 2n of 64x64 tiles) ----
__global__ __launch_bounds__(512, 4) void main_gemm(
    const float* __restrict__ x, const float* __restrict__ px,
    const float* __restrict__ noise,
    const float* __restrict__ hW, const float* __restrict__ hb,
    const float* __restrict__ pW, const float* __restrict__ pb,
    float* __restrict__ out)
{
    // W tile double buffer [2][128 o][136 halfs]. 69632 B.
    // Prologue overlay (both buffers): noise staging [256 b][136 halfs].
    __shared__ __attribute__((aligned(16))) _Float16 Bl[2][128 * 136];
    __shared__ __attribute__((aligned(16))) _Float16 xhl[256 * 16];  // 8192 B

    const int t = threadIdx.x;
    // sibling swizzle: the 2 b-tile blocks of one W-slab group are 8 apart in
    // linear index -> same XCD under round-robin -> L2 serves second read.
    const int lin = blockIdx.x;          // 0..511
    const int r   = lin & 7;
    const int s   = (lin >> 3) & 1;      // b-tile sibling
    const int g   = (lin >> 4) * 8 + r;  // 0..255 slab group
    const int z   = g >> 2;              // 0..63: branch*32 + ichunk
    const int y   = g & 3;               // o-tile
    const int b0  = s * 256;
    const int o0  = y * 128;
    const int branch = z >> 5;
    const int ic0 = (z & 31) * 16;       // 16 i's per block
    const float* __restrict__ xsrc = branch ? px : x;
    const float* __restrict__ Ws   = branch ? pW : hW;
    const float* __restrict__ bias = branch ? pb : hb;
    const int nmacro = ((z & 31) == 0) ? 17 : 16;   // +E2 tail slab

    // ---- stage x tile 256b x 16i -> half, stride 16 (scalar-read only) ----
#pragma unroll
    for (int k = 0; k < 2; ++k) {
        int idx = k * 512 + t;           // 0..1023
        int bb = idx >> 2, c = (idx & 3) * 4;
        float4 v = *(const float4*)(xsrc + (b0 + bb) * 512 + ic0 + c);
        *(unsigned*)&xhl[bb * 16 + c]     = pk2(v.x, v.y);
        *(unsigned*)&xhl[bb * 16 + c + 2] = pk2(v.z, v.w);
    }
    // ---- stage noise 256b x 128n -> half into Bl overlay, stride 136 ----
    _Float16* nzl = &Bl[0][0];
#pragma unroll
    for (int k = 0; k < 16; ++k) {
        int idx = k * 512 + t;           // 0..8191
        int bb = idx >> 5, c = (idx & 31) * 4;
        float4 v = *(const float4*)(noise + (b0 + bb) * 128 + c);
        *(unsigned*)&nzl[bb * 136 + c]     = pk2(v.x, v.y);
        *(unsigned*)&nzl[bb * 136 + c + 2] = pk2(v.z, v.w);
    }
    __syncthreads();

    const int lane = t & 63;
    const int w    = t >> 6;
    const int wm64 = (w >> 1) * 64;      // 0,64,128,192
    const int wn64 = (w & 1) * 64;       // 0,64
    const int quad = lane >> 4;
    const int l16  = lane & 15;

    // noise A-fragments in registers
    half8 nzf[4][4];
#pragma unroll
    for (int mf = 0; mf < 4; ++mf)
#pragma unroll
        for (int q = 0; q < 4; ++q)
            nzf[mf][q] = *(half8*)&nzl[(wm64 + mf * 16 + l16) * 136 + q * 32 + quad * 8];

    floatx4 acc[4][4];
#pragma unroll
    for (int a = 0; a < 4; ++a)
#pragma unroll
        for (int b = 0; b < 4; ++b) acc[a][b] = (floatx4)0.0f;

    // W slab prefetch regs: thread -> 4 chunks of 8 contiguous floats
    float4 wa[4], wb[4];
    {
        const float* p = Ws + (long)(ic0 * 512 + o0) * 128;
#pragma unroll
        for (int j = 0; j < 4; ++j) {
            int c = j * 512 + t;
            int off = (c >> 4) * 128 + (c & 15) * 8;
            wa[j] = *(const float4*)(p + off);
            wb[j] = *(const float4*)(p + off + 4);
        }
    }
    __syncthreads();   // nzf overlay reads complete before first Bl write

    for (int m = 0; m < nmacro; ++m) {
        _Float16* buf = &Bl[m & 1][0];
#pragma unroll
        for (int j = 0; j < 4; ++j) {
            int c = j * 512 + t;
            int row = c >> 4, col8 = (c & 15) * 8;
            *(uint4*)&buf[row * 136 + col8] = make_uint4(
                pk2(wa[j].x, wa[j].y), pk2(wa[j].z, wa[j].w),
                pk2(wb[j].x, wb[j].y), pk2(wb[j].z, wb[j].w));
        }
        __syncthreads();                 // one barrier per macro (dbuf-safe)
        if (m + 1 < nmacro) {            // prefetch next slab over MFMA phase
            long rb = (m + 1 < 16) ? (long)((ic0 + m + 1) * 512 + o0)
                                   : (long)(MAIN_D + o0);
            const float* p = Ws + rb * 128;
#pragma unroll
            for (int j = 0; j < 4; ++j) {
                int c = j * 512 + t;
                int off = (c >> 4) * 128 + (c & 15) * 8;
                wa[j] = *(const float4*)(p + off);
                wb[j] = *(const float4*)(p + off + 4);
            }
        }
        const bool isE2 = (m >= 16);
        _Float16 xs[4];
        if (!isE2) {
#pragma unroll
            for (int mf = 0; mf < 4; ++mf)
                xs[mf] = xhl[(wm64 + mf * 16 + l16) * 16 + m];
        }
#pragma unroll
        for (int q = 0; q < 4; ++q) {
            half8 bfr[4], afr[4];
#pragma unroll
            for (int nf = 0; nf < 4; ++nf)
                bfr[nf] = *(half8*)&buf[(wn64 + nf * 16 + l16) * 136 + q * 32 + quad * 8];
#pragma unroll
            for (int mf = 0; mf < 4; ++mf) {
                if (isE2) afr[mf] = nzf[mf][q];
                else {
                    half8 xv;
#pragma unroll
                    for (int j = 0; j < 8; ++j) xv[j] = xs[mf];
                    afr[mf] = nzf[mf][q] * xv;
                }
            }
#pragma unroll
            for (int mf = 0; mf < 4; ++mf)
#pragma unroll
                for (int nf = 0; nf < 4; ++nf)
                    acc[mf][nf] = __builtin_amdgcn_mfma_f32_16x16x32_f16(
                        afr[mf], bfr[nf], acc[mf][nf], 0, 0, 0);
        }
    }

    // ---- E1: bias step, K=16 zero-padded to 32 (A from xhl, B staged) ----
    __syncthreads();
    {
        const int row = t >> 2, c8 = (t & 3) * 8;   // 128 rows x 32 cols
        float tmp[8];
#pragma unroll
        for (int j = 0; j < 8; ++j) {
            int col = c8 + j;
            tmp[j] = (col < 16) ? bias[(long)(ic0 + col) * 512 + o0 + row] : 0.0f;
        }
        *(uint4*)&Bl[0][row * 136 + c8] = make_uint4(
            pk2(tmp[0], tmp[1]), pk2(tmp[2], tmp[3]),
            pk2(tmp[4], tmp[5]), pk2(tmp[6], tmp[7]));
    }
    __syncthreads();
    {
        half8 afr[4], bfr[4];
#pragma unroll
        for (int mf = 0; mf < 4; ++mf) {
            if (quad < 2)
                afr[mf] = *(half8*)&xhl[(wm64 + mf * 16 + l16) * 16 + quad * 8];
            else
                afr[mf] = (half8)(_Float16)0;   // k >= 16: zero pad
        }
#pragma unroll
        for (int nf = 0; nf < 4; ++nf)
            bfr[nf] = *(half8*)&Bl[0][(wn64 + nf * 16 + l16) * 136 + quad * 8];
#pragma unroll
        for (int mf = 0; mf < 4; ++mf)
#pragma unroll
            for (int nf = 0; nf < 4; ++nf)
                acc[mf][nf] = __builtin_amdgcn_mfma_f32_16x16x32_f16(
                    afr[mf], bfr[nf], acc[mf][nf], 0, 0, 0);
    }

    // ---- split-K accumulate (C/D: row=quad*4+r, col=l16) ----
#pragma unroll
    for (int mf = 0; mf < 4; ++mf)
#pragma unroll
        for (int nf = 0; nf < 4; ++nf)
#pragma unroll
            for (int rr = 0; rr < 4; ++rr) {
                int row = b0 + wm64 + mf * 16 + quad * 4 + rr;
                int col = o0 + wn64 + nf * 16 + l16;
                atomicAdd(out + row * 512 + col, acc[mf][nf][rr]);
            }
}

extern "C" void kernel_launch(void* const* d_in, const int* in_sizes, int n_in,
                              void* d_out, int out_size, void* d_ws, size_t ws_size,
                              hipStream_t stream) {
    const float* x  = (const float*)d_in[0];
    const float* px = (const float*)d_in[1];
    const float* nz = (const float*)d_in[2];
    const float* hW = (const float*)d_in[3];
    const float* hb = (const float*)d_in[4];
    const float* pW = (const float*)d_in[5];
    const float* pb = (const float*)d_in[6];
    float* out = (float*)d_out;

    hipLaunchKernelGGL(init_kernel, dim3(256), dim3(256), 0, stream, hb, pb, out);
    hipLaunchKernelGGL(main_gemm, dim3(512), dim3(512), 0, stream,
                       x, px, nz, hW, hb, pW, pb, out);
}